// Round 7
// baseline (155.338 us; speedup 1.0000x reference)
//
#include <hip/hip_runtime.h>
#include <math.h>

#define BATCH 64
#define DK 256
#define FEATURES 512
#define NUM_TAPE 2048
#define TOPK 512
#define TOP16 16
#define THRESH 4.0f
#define KCHUNKS 8
#define KPER (TOPK / KCHUNKS) /* 64 */
#define TIECAP 640

// output layout (floats)
#define OFF_Q 0
#define OFF_HP (BATCH * DK)                    /* 16384 */
#define OFF_REM (OFF_HP + BATCH)               /* 16448 */
#define OFF_NUP (OFF_REM + BATCH)              /* 16512 */
#define OFF_MASK (OFF_NUP + BATCH)             /* 16576 */
#define OFF_TSEL (OFF_MASK + BATCH * NUM_TAPE) /* 147648 */

// ws layout (floats)
#define WS_SCORES 0      /* 64*2048 */
#define WS_TOPK 131072   /* int, 64*512 */
#define WS_WEIGHTS 163840
#define WS_PART 196608   /* 64*8*512 */
#define WS_TICK 458752   /* unsigned cnt1[64] — self-cleaning via atomicInc wrap */

__device__ __forceinline__ unsigned f2key(float f) {
    unsigned u = __float_as_uint(f);
    return (u & 0x80000000u) ? ~u : (u | 0x80000000u);
}

// ---------------- Kernel A: scores[b][n] = dot(q[b,:256], tape[b,n,:256]) ----------
__global__ __launch_bounds__(256) void k_scores(const float* __restrict__ q,
                                                const float* __restrict__ tape,
                                                float* __restrict__ scores) {
    const int b = blockIdx.y;
    const int wave = threadIdx.x >> 6;
    const int lane = threadIdx.x & 63;
    const float4 qf = reinterpret_cast<const float4*>(q + b * DK)[lane];
    const int base = blockIdx.x * 32;
#pragma unroll
    for (int t = 0; t < 8; ++t) {
        const int tok = base + wave + 4 * t;
        const float4 tf =
            reinterpret_cast<const float4*>(tape + ((size_t)b * NUM_TAPE + tok) * FEATURES)[lane];
        float s = qf.x * tf.x + qf.y * tf.y + qf.z * tf.z + qf.w * tf.w;
#pragma unroll
        for (int off = 32; off; off >>= 1) s += __shfl_xor(s, off);
        if (lane == 0) scores[b * NUM_TAPE + tok] = s;
    }
}

// ---------------- Kernel B: per-batch radix-select top-k + softmax + scalars --------
__global__ __launch_bounds__(512) void k_topk(const float* __restrict__ scores,
                                              const float* __restrict__ mask_in,
                                              const float* __restrict__ hp_in,
                                              const float* __restrict__ rem_in,
                                              const float* __restrict__ nup_in,
                                              int* __restrict__ topk_ws,
                                              float* __restrict__ weights_ws,
                                              float* __restrict__ out) {
    const int b = blockIdx.x;
    const int tid = threadIdx.x;
    const int lane = tid & 63;
    const int wv = tid >> 6;
    __shared__ int hist[256];
    __shared__ int chunkTot[4];
    __shared__ int sh_digit, sh_hi;
    __shared__ int sel_idx[TOPK];
    __shared__ unsigned sel_key[TOPK];
    __shared__ float redf[8];
    __shared__ int tie_idx[TIECAP];
    __shared__ int tie_cnt, sel_cnt;
    __shared__ int in16_idx[TOP16];

    // 4 elements per thread, float4-coalesced: e = 4*tid + j
    const float4 sc = reinterpret_cast<const float4*>(scores + (size_t)b * NUM_TAPE)[tid];
    const float4 mk = reinterpret_cast<const float4*>(mask_in + (size_t)b * NUM_TAPE)[tid];
    unsigned key[4];
    key[0] = f2key(sc.x - mk.x * 1e9f);
    key[1] = f2key(sc.y - mk.y * 1e9f);
    key[2] = f2key(sc.z - mk.z * 1e9f);
    key[3] = f2key(sc.w - mk.w * 1e9f);

    // ---- radix select 1: k = 512 over 2048 keys
    unsigned prefix = 0;
    int krem = TOPK;
#pragma unroll
    for (int p = 0; p < 4; ++p) {
        const int shift = 24 - 8 * p;
        if (tid < 256) hist[tid] = 0;
        __syncthreads();
#pragma unroll
        for (int i = 0; i < 4; ++i) {
            const unsigned kk = key[i];
            const bool act = (p == 0) || ((kk >> (shift + 8)) == (prefix >> (shift + 8)));
            if (act) atomicAdd(&hist[(kk >> shift) & 0xFF], 1);
        }
        __syncthreads();
        int v = 0, hcnt = 0;
        if (tid < 256) {
            hcnt = hist[tid];
            v = hcnt;
#pragma unroll
            for (int off = 1; off < 64; off <<= 1) {
                const int t = __shfl_down(v, off);
                if (lane + off < 64) v += t;
            }
            if (lane == 0) chunkTot[wv] = v;
        }
        __syncthreads();
        if (tid < 256) {
#pragma unroll
            for (int w2 = 0; w2 < 4; ++w2)
                if (w2 > wv) v += chunkTot[w2];
            if (v >= krem && (v - hcnt) < krem) {
                sh_digit = tid;
                sh_hi = v - hcnt;
            }
        }
        __syncthreads();
        prefix |= ((unsigned)sh_digit) << shift;
        krem -= sh_hi;
        __syncthreads();
    }
    const unsigned T512 = prefix;
    const int krem512 = krem;

    // ---- compaction: key > T512 plus first krem512 ties (ascending index)
    if (tid == 0) {
        sel_cnt = 0;
        tie_cnt = 0;
    }
    __syncthreads();
#pragma unroll
    for (int i = 0; i < 4; ++i) {
        const int e = 4 * tid + i;
        const unsigned kk = key[i];
        if (kk > T512) {
            const int p = atomicAdd(&sel_cnt, 1);
            sel_idx[p] = e;
            sel_key[p] = kk;
        } else if (kk == T512) {
            const int p = atomicAdd(&tie_cnt, 1);
            if (p < TIECAP) tie_idx[p] = e;
        }
    }
    __syncthreads();
    int tc = tie_cnt < TIECAP ? tie_cnt : TIECAP;
    for (int t = tid; t < tc; t += 512) {
        const int my = tie_idx[t];
        int rank = 0;
        for (int u = 0; u < tc; ++u) rank += (tie_idx[u] < my);
        if (rank < krem512) {
            const int p = atomicAdd(&sel_cnt, 1);
            sel_idx[p] = my;
            sel_key[p] = T512;
        }
    }
    __syncthreads();

    // ---- radix select 2: k = 16 over the 512 selected keys (1/thread)
    const unsigned kk2 = sel_key[tid];
    prefix = 0;
    krem = TOP16;
#pragma unroll
    for (int p = 0; p < 4; ++p) {
        const int shift = 24 - 8 * p;
        if (tid < 256) hist[tid] = 0;
        __syncthreads();
        {
            const bool act = (p == 0) || ((kk2 >> (shift + 8)) == (prefix >> (shift + 8)));
            if (act) atomicAdd(&hist[(kk2 >> shift) & 0xFF], 1);
        }
        __syncthreads();
        int v = 0, hcnt = 0;
        if (tid < 256) {
            hcnt = hist[tid];
            v = hcnt;
#pragma unroll
            for (int off = 1; off < 64; off <<= 1) {
                const int t = __shfl_down(v, off);
                if (lane + off < 64) v += t;
            }
            if (lane == 0) chunkTot[wv] = v;
        }
        __syncthreads();
        if (tid < 256) {
#pragma unroll
            for (int w2 = 0; w2 < 4; ++w2)
                if (w2 > wv) v += chunkTot[w2];
            if (v >= krem && (v - hcnt) < krem) {
                sh_digit = tid;
                sh_hi = v - hcnt;
            }
        }
        __syncthreads();
        prefix |= ((unsigned)sh_digit) << shift;
        krem -= sh_hi;
        __syncthreads();
    }
    const unsigned T16 = prefix;
    const int krem16 = krem;

    // ---- top16 boundary-tie membership (ascending original index)
    if (tid == 0) tie_cnt = 0;
    __syncthreads();
    if (kk2 == T16) {
        const int p = atomicAdd(&tie_cnt, 1);
        if (p < TIECAP) tie_idx[p] = sel_idx[tid];
    }
    __syncthreads();
    tc = tie_cnt < TIECAP ? tie_cnt : TIECAP;
    for (int t = tid; t < tc; t += 512) {
        const int my = tie_idx[t];
        int rank = 0;
        for (int u = 0; u < tc; ++u) rank += (tie_idx[u] < my);
        if (rank < krem16) in16_idx[rank] = my;
    }
    __syncthreads();

    // ---- softmax over row-0 scores at selected idx (jnp.take flatten semantics)
    const int myidx = sel_idx[tid];
    const float wraw = scores[myidx] * 0.0625f; // scores[0, idx] / sqrt(256)

    float m = wraw;
#pragma unroll
    for (int off = 32; off; off >>= 1) m = fmaxf(m, __shfl_xor(m, off));
    if (lane == 0) redf[wv] = m;
    __syncthreads();
#pragma unroll
    for (int w2 = 0; w2 < 8; ++w2) m = fmaxf(m, redf[w2]);
    __syncthreads();

    const float e = expf(wraw - m);
    float s = e;
#pragma unroll
    for (int off = 32; off; off >>= 1) s += __shfl_xor(s, off);
    if (lane == 0) redf[wv] = s;
    __syncthreads();
    s = 0.f;
#pragma unroll
    for (int w2 = 0; w2 < 8; ++w2) s += redf[w2];
    __syncthreads();

    const float w = e / s;
    weights_ws[b * TOPK + tid] = w;
    topk_ws[b * TOPK + tid] = myidx;

    float lsq = w * w;
#pragma unroll
    for (int off = 32; off; off >>= 1) lsq += __shfl_xor(lsq, off);
    if (lane == 0) redf[wv] = lsq;
    __syncthreads();
    float sumsq = 0.f;
#pragma unroll
    for (int w2 = 0; w2 < 8; ++w2) sumsq += redf[w2];
    __syncthreads();

    bool in16 = (kk2 > T16);
    if (kk2 == T16) {
        for (int u = 0; u < krem16; ++u)
            if (in16_idx[u] == myidx) in16 = true;
    }
    float l16 = in16 ? w : 0.f;
#pragma unroll
    for (int off = 32; off; off >>= 1) l16 += __shfl_xor(l16, off);
    if (lane == 0) redf[wv] = l16;
    __syncthreads();
    float s16 = 0.f;
#pragma unroll
    for (int w2 = 0; w2 < 8; ++w2) s16 += redf[w2];

    if (tid == 0) {
        const float hp = hp_in[b], rem = rem_in[b], nup = nup_in[b];
        const float entropy = 1.0f - sumsq;
        const float still = (hp < THRESH) ? 1.f : 0.f;
        const float nh = ((hp + s16) >= THRESH ? 1.f : 0.f) * still;
        const float st2 = still - nh;
        out[OFF_REM + b] = rem + (nh + st2) * entropy;
        float hp1 = hp + s16 * st2;
        hp1 = hp1 + nh * (THRESH - hp1);
        out[OFF_HP + b] = hp1;
        out[OFF_NUP + b] = nup + st2 + nh;
    }

    // score_mask: copy row (we already hold it as mk), then +1 at selected
    reinterpret_cast<float4*>(out + OFF_MASK + (size_t)b * NUM_TAPE)[tid] = mk;
    __syncthreads();
    out[OFF_MASK + b * NUM_TAPE + myidx] = mask_in[b * NUM_TAPE + myidx] + 1.0f;
}

// ======== Kernel C: gather partials + (last chunk per batch) finish ==========
// Ticket counter uses atomicInc wrap semantics: poisoned/stale value >= 7 resets
// to 0 on first arrival; every replay leaves the counter at 7, so the pattern is
// self-cleaning with no memset/init. Winner = arrival observing old == KCHUNKS-2.
__global__ __launch_bounds__(512) void k_gather_finish(
    const float* __restrict__ tape, const int* __restrict__ topk_ws,
    const float* __restrict__ weights_ws, const float* __restrict__ q,
    float* __restrict__ partials, unsigned* __restrict__ cnt1, float* __restrict__ out) {
    const int b = blockIdx.y;
    const int kc = blockIdx.x;
    const int tid = threadIdx.x;
    const int rs = tid >> 7;   // 0..3 row-subgroup
    const int f4 = tid & 127;  // float4 feature index
    __shared__ float wsh[KPER];
    __shared__ int ish[KPER];
    __shared__ float4 shacc[512];
    __shared__ int sh_win;
    if (tid < KPER) {
        wsh[tid] = weights_ws[b * TOPK + kc * KPER + tid];
        ish[tid] = topk_ws[b * TOPK + kc * KPER + tid];
    }
    __syncthreads();
    float4 acc = {0.f, 0.f, 0.f, 0.f};
#pragma unroll 4
    for (int k = rs; k < KPER; k += 4) {
        const float w = wsh[k];
        const float4 t =
            reinterpret_cast<const float4*>(tape + ((size_t)b * NUM_TAPE + ish[k]) * FEATURES)[f4];
        acc.x = fmaf(w, t.x, acc.x);
        acc.y = fmaf(w, t.y, acc.y);
        acc.z = fmaf(w, t.z, acc.z);
        acc.w = fmaf(w, t.w, acc.w);
    }
    shacc[tid] = acc;
    __syncthreads();
    if (tid < 128) {
        const float4 a0 = shacc[f4];
        const float4 a1 = shacc[128 + f4];
        const float4 a2 = shacc[256 + f4];
        const float4 a3 = shacc[384 + f4];
        float4 r;
        r.x = (a0.x + a1.x) + (a2.x + a3.x);
        r.y = (a0.y + a1.y) + (a2.y + a3.y);
        r.z = (a0.z + a1.z) + (a2.z + a3.z);
        r.w = (a0.w + a1.w) + (a2.w + a3.w);
        reinterpret_cast<float4*>(partials + ((size_t)b * KCHUNKS + kc) * FEATURES)[f4] = r;
    }
    __threadfence();
    __syncthreads();
    if (tid == 0) {
        const unsigned old = atomicInc(&cnt1[b], KCHUNKS - 1);
        sh_win = (old == KCHUNKS - 2) ? 1 : 0;
    }
    __syncthreads();
    if (!sh_win) return;
    __threadfence();  // acquire: all 8 chunk partials for batch b visible

    // ---- finish: reduce 8 partials -> token_sel + query update
    const float4* pp = reinterpret_cast<const float4*>(partials + (size_t)b * KCHUNKS * FEATURES);
    const int g = tid >> 7;
    const float4 a = pp[g * 128 + f4];
    const float4 c = pp[(g + 4) * 128 + f4];
    float4 r;
    r.x = a.x + c.x;
    r.y = a.y + c.y;
    r.z = a.z + c.z;
    r.w = a.w + c.w;
    shacc[tid] = r;
    __syncthreads();
    if (tid < 128) {
        const float4 s0 = shacc[f4];
        const float4 s1 = shacc[128 + f4];
        const float4 s2 = shacc[256 + f4];
        const float4 s3 = shacc[384 + f4];
        float4 sS;
        sS.x = (s0.x + s1.x) + (s2.x + s3.x);
        sS.y = (s0.y + s1.y) + (s2.y + s3.y);
        sS.z = (s0.z + s1.z) + (s2.z + s3.z);
        sS.w = (s0.w + s1.w) + (s2.w + s3.w);
        reinterpret_cast<float4*>(out + OFF_TSEL + (size_t)b * FEATURES)[f4] = sS;
        if (f4 < 64) {
            const float4 qv = reinterpret_cast<const float4*>(q + (size_t)b * DK)[f4];
            float4 nq;
            nq.x = (qv.x + sS.x) * 0.5f;
            nq.y = (qv.y + sS.y) * 0.5f;
            nq.z = (qv.z + sS.z) * 0.5f;
            nq.w = (qv.w + sS.w) * 0.5f;
            reinterpret_cast<float4*>(out + OFF_Q + (size_t)b * DK)[f4] = nq;
        }
    }
}

extern "C" void kernel_launch(void* const* d_in, const int* in_sizes, int n_in,
                              void* d_out, int out_size, void* d_ws, size_t ws_size,
                              hipStream_t stream) {
    const float* q = (const float*)d_in[0];
    const float* hp = (const float*)d_in[1];
    const float* rem = (const float*)d_in[2];
    const float* nup = (const float*)d_in[3];
    const float* mask = (const float*)d_in[4];
    const float* tape = (const float*)d_in[5];
    float* out = (float*)d_out;
    float* ws = (float*)d_ws;

    float* scores = ws + WS_SCORES;
    int* topk = (int*)(ws + WS_TOPK);
    float* weights = ws + WS_WEIGHTS;
    float* partials = ws + WS_PART;
    unsigned* cnt1 = (unsigned*)(ws + WS_TICK);

    k_scores<<<dim3(NUM_TAPE / 32, BATCH), 256, 0, stream>>>(q, tape, scores);
    k_topk<<<BATCH, 512, 0, stream>>>(scores, mask, hp, rem, nup, topk, weights, out);
    k_gather_finish<<<dim3(KCHUNKS, BATCH), 512, 0, stream>>>(
        tape, topk, weights, q, partials, cnt1, out);
}

// Round 8
// 53.897 us; speedup vs baseline: 2.8821x; 2.8821x over previous
//
#include <hip/hip_runtime.h>
#include <math.h>

#define BATCH 64
#define DK 256
#define FEATURES 512
#define NUM_TAPE 2048
#define TOPK 512
#define TOP16 16
#define THRESH 4.0f
#define KCHUNKS 8
#define RANGE (NUM_TAPE / KCHUNKS) /* 256 original-index range per gather block */
#define CAP 640                    /* candidate list cap (typ. <10 for continuous data) */

// output layout (floats)
#define OFF_Q 0
#define OFF_HP (BATCH * DK)                    /* 16384 */
#define OFF_REM (OFF_HP + BATCH)               /* 16448 */
#define OFF_NUP (OFF_REM + BATCH)              /* 16512 */
#define OFF_MASK (OFF_NUP + BATCH)             /* 16576 */
#define OFF_TSEL (OFF_MASK + BATCH * NUM_TAPE) /* 147648 */

// ws layout (floats)
#define WS_SCORES 0    /* 64*2048 */
#define WS_PART 131072 /* 64*8*512 */

__device__ __forceinline__ unsigned f2key(float f) {
    unsigned u = __float_as_uint(f);
    return (u & 0x80000000u) ? ~u : (u | 0x80000000u);
}

// find descending-order bucket: sh_digit = d with suffix(d) >= KREM > suffix(d+1),
// sh_hi = suffix(d+1). hist[256] valid on entry; all 512 threads participate.
#define RADIX_FIND(KREM)                                              \
    {                                                                 \
        int v = 0, hcnt = 0;                                          \
        if (tid < 256) {                                              \
            hcnt = hist[tid];                                         \
            v = hcnt;                                                 \
            _Pragma("unroll") for (int off = 1; off < 64; off <<= 1) {\
                const int t = __shfl_down(v, off);                    \
                if (lane + off < 64) v += t;                          \
            }                                                         \
            if (lane == 0) chunkTot[wv] = v;                          \
        }                                                             \
        __syncthreads();                                              \
        if (tid < 256) {                                              \
            _Pragma("unroll") for (int w2 = 0; w2 < 4; ++w2)          \
                if (w2 > wv) v += chunkTot[w2];                       \
            if (v >= (KREM) && (v - hcnt) < (KREM)) {                 \
                sh_digit = tid;                                       \
                sh_hi = v - hcnt;                                     \
            }                                                         \
        }                                                             \
        __syncthreads();                                              \
    }

__device__ __forceinline__ float block_max8(float v, volatile float* redf, int lane, int wv) {
#pragma unroll
    for (int off = 32; off; off >>= 1) v = fmaxf(v, __shfl_xor(v, off));
    if (lane == 0) redf[wv] = v;
    __syncthreads();
#pragma unroll
    for (int w2 = 0; w2 < 8; ++w2) v = fmaxf(v, redf[w2]);
    __syncthreads();
    return v;
}

__device__ __forceinline__ float block_sum8(float v, volatile float* redf, int lane, int wv) {
#pragma unroll
    for (int off = 32; off; off >>= 1) v += __shfl_xor(v, off);
    if (lane == 0) redf[wv] = v;
    __syncthreads();
    float s = 0.f;
#pragma unroll
    for (int w2 = 0; w2 < 8; ++w2) s += redf[w2];
    __syncthreads();
    return s;
}

// ---------------- Kernel A: scores[b][n] = dot(q[b,:256], tape[b,n,:256]) ----------
__global__ __launch_bounds__(256) void k_scores(const float* __restrict__ q,
                                                const float* __restrict__ tape,
                                                float* __restrict__ scores) {
    const int b = blockIdx.y;
    const int wave = threadIdx.x >> 6;
    const int lane = threadIdx.x & 63;
    const float4 qf = reinterpret_cast<const float4*>(q + b * DK)[lane];
    const int base = blockIdx.x * 32;
#pragma unroll
    for (int t = 0; t < 8; ++t) {
        const int tok = base + wave + 4 * t;
        const float4 tf =
            reinterpret_cast<const float4*>(tape + ((size_t)b * NUM_TAPE + tok) * FEATURES)[lane];
        float s = qf.x * tf.x + qf.y * tf.y + qf.z * tf.z + qf.w * tf.w;
#pragma unroll
        for (int off = 32; off; off >>= 1) s += __shfl_xor(s, off);
        if (lane == 0) scores[b * NUM_TAPE + tok] = s;
    }
}

// ======== Kernel B: redundant deterministic select + range-partitioned gather ========
// Each block (kc, b) re-runs the identical top-512 selection for batch b (no
// cross-block sync -- identical inputs + identical code => identical results),
// then gathers selected tokens with original index in [kc*256, (kc+1)*256).
__global__ __launch_bounds__(512) void k_select_gather(
    const float* __restrict__ scores, const float* __restrict__ mask_in,
    const float* __restrict__ hp_in, const float* __restrict__ rem_in,
    const float* __restrict__ nup_in, const float* __restrict__ tape,
    float* __restrict__ partials, float* __restrict__ out) {
    const int b = blockIdx.y;
    const int kc = blockIdx.x;
    const int tid = threadIdx.x;
    const int lane = tid & 63;
    const int wv = tid >> 6;

    __shared__ int hist[256];
    __shared__ int chunkTot[4];
    __shared__ int sh_digit, sh_hi;
    __shared__ unsigned ckey[CAP];
    __shared__ int cidx[CAP];
    __shared__ int csel[CAP];
    __shared__ int cand_n;
    __shared__ float redf[8];
    __shared__ int gl_idx[RANGE];
    __shared__ float gl_w[RANGE];
    __shared__ int gl_n;
    __shared__ float4 shacc[512];

    // ---- load: 4 elements/thread, e = 4*tid + j
    const float4 sc = reinterpret_cast<const float4*>(scores + (size_t)b * NUM_TAPE)[tid];
    const float4 mk = reinterpret_cast<const float4*>(mask_in + (size_t)b * NUM_TAPE)[tid];
    const float4 s0 = reinterpret_cast<const float4*>(scores)[tid]; // row 0 (flatten bug)
    unsigned key[4];
    key[0] = f2key(sc.x - mk.x * 1e9f);
    key[1] = f2key(sc.y - mk.y * 1e9f);
    key[2] = f2key(sc.z - mk.z * 1e9f);
    key[3] = f2key(sc.w - mk.w * 1e9f);
    float s0v[4] = {s0.x * 0.0625f, s0.y * 0.0625f, s0.z * 0.0625f, s0.w * 0.0625f};
    float mkv[4] = {mk.x, mk.y, mk.z, mk.w};

    // ---- select-1 (top-512): pass A on byte3
    if (tid < 256) hist[tid] = 0;
    __syncthreads();
#pragma unroll
    for (int j = 0; j < 4; ++j) atomicAdd(&hist[key[j] >> 24], 1);
    __syncthreads();
    RADIX_FIND(TOPK);
    const unsigned B1 = (unsigned)sh_digit;
    const int above1 = sh_hi;
    __syncthreads();

    // pass B on byte2 among keys with byte3 == B1
    if (tid < 256) hist[tid] = 0;
    __syncthreads();
#pragma unroll
    for (int j = 0; j < 4; ++j)
        if ((key[j] >> 24) == B1) atomicAdd(&hist[(key[j] >> 16) & 0xFF], 1);
    __syncthreads();
    const int kremB = TOPK - above1;
    RADIX_FIND(kremB);
    const unsigned P16 = (B1 << 8) | (unsigned)sh_digit;
    const int krem512 = kremB - sh_hi;
    __syncthreads();

    // candidates (16-bit prefix == P16): exact rank by (key desc, idx asc)
    if (tid == 0) cand_n = 0;
    __syncthreads();
    int cpos[4];
#pragma unroll
    for (int j = 0; j < 4; ++j) {
        cpos[j] = -1;
        if ((key[j] >> 16) == P16) {
            const int p = atomicAdd(&cand_n, 1);
            if (p < CAP) {
                ckey[p] = key[j];
                cidx[p] = 4 * tid + j;
            }
            cpos[j] = p;
        }
    }
    __syncthreads();
    int cn = cand_n < CAP ? cand_n : CAP;
    for (int t = tid; t < cn; t += 512) {
        const unsigned k = ckey[t];
        const int i = cidx[t];
        int r = 0;
        for (int u = 0; u < cn; ++u) {
            const unsigned ko = ckey[u];
            r += (ko > k) || (ko == k && cidx[u] < i);
        }
        csel[t] = (r < krem512);
    }
    __syncthreads();
    bool sel[4];
#pragma unroll
    for (int j = 0; j < 4; ++j)
        sel[j] = ((key[j] >> 16) > P16) ||
                 (cpos[j] >= 0 && cpos[j] < CAP && csel[cpos[j]]);
    __syncthreads();

    // ---- select-2 (top-16 among selected): pass C on byte3 + exact rank
    if (tid < 256) hist[tid] = 0;
    __syncthreads();
#pragma unroll
    for (int j = 0; j < 4; ++j)
        if (sel[j]) atomicAdd(&hist[key[j] >> 24], 1);
    __syncthreads();
    RADIX_FIND(TOP16);
    const unsigned C1 = (unsigned)sh_digit;
    const int krem16 = TOP16 - sh_hi;
    __syncthreads();

    if (tid == 0) cand_n = 0;
    __syncthreads();
    int c2pos[4];
#pragma unroll
    for (int j = 0; j < 4; ++j) {
        c2pos[j] = -1;
        if (sel[j] && (key[j] >> 24) == C1) {
            const int p = atomicAdd(&cand_n, 1);
            if (p < CAP) {
                ckey[p] = key[j];
                cidx[p] = 4 * tid + j;
            }
            c2pos[j] = p;
        }
    }
    __syncthreads();
    cn = cand_n < CAP ? cand_n : CAP;
    for (int t = tid; t < cn; t += 512) {
        const unsigned k = ckey[t];
        const int i = cidx[t];
        int r = 0;
        for (int u = 0; u < cn; ++u) {
            const unsigned ko = ckey[u];
            r += (ko > k) || (ko == k && cidx[u] < i);
        }
        csel[t] = (r < krem16);
    }
    __syncthreads();
    bool in16[4];
#pragma unroll
    for (int j = 0; j < 4; ++j)
        in16[j] = sel[j] && (((key[j] >> 24) > C1) ||
                             (c2pos[j] >= 0 && c2pos[j] < CAP && csel[c2pos[j]]));

    // ---- softmax over row-0 scores at selected elements
    float mloc = -3e38f;
#pragma unroll
    for (int j = 0; j < 4; ++j)
        if (sel[j]) mloc = fmaxf(mloc, s0v[j]);
    const float m = block_max8(mloc, redf, lane, wv);

    float ev[4];
    float eloc = 0.f;
#pragma unroll
    for (int j = 0; j < 4; ++j) {
        ev[j] = sel[j] ? expf(s0v[j] - m) : 0.f;
        eloc += ev[j];
    }
    const float ssum = block_sum8(eloc, redf, lane, wv);
    const float inv = 1.0f / ssum;

    float w[4];
    float lsq = 0.f, l16 = 0.f;
#pragma unroll
    for (int j = 0; j < 4; ++j) {
        w[j] = ev[j] * inv;
        lsq += w[j] * w[j];
        if (in16[j]) l16 += w[j];
    }
    const float sumsq = block_sum8(lsq, redf, lane, wv);
    const float s16 = block_sum8(l16, redf, lane, wv);

    // ---- kc==0 writes scalars + mask (flags are thread-local, no scatter)
    if (kc == 0) {
        float4 om;
        om.x = mkv[0] + (sel[0] ? 1.f : 0.f);
        om.y = mkv[1] + (sel[1] ? 1.f : 0.f);
        om.z = mkv[2] + (sel[2] ? 1.f : 0.f);
        om.w = mkv[3] + (sel[3] ? 1.f : 0.f);
        reinterpret_cast<float4*>(out + OFF_MASK + (size_t)b * NUM_TAPE)[tid] = om;
        if (tid == 0) {
            const float hp = hp_in[b], rem = rem_in[b], nup = nup_in[b];
            const float entropy = 1.0f - sumsq;
            const float still = (hp < THRESH) ? 1.f : 0.f;
            const float nh = ((hp + s16) >= THRESH ? 1.f : 0.f) * still;
            const float st2 = still - nh;
            out[OFF_REM + b] = rem + (nh + st2) * entropy;
            float hp1 = hp + s16 * st2;
            hp1 = hp1 + nh * (THRESH - hp1);
            out[OFF_HP + b] = hp1;
            out[OFF_NUP + b] = nup + st2 + nh;
        }
    }

    // ---- deterministic compaction of this block's index range [kc*256,(kc+1)*256)
    // wave kc holds exactly those elements (threads 64*kc..64*kc+63)
    if (wv == kc) {
        const int cnt = (sel[0] ? 1 : 0) + (sel[1] ? 1 : 0) + (sel[2] ? 1 : 0) + (sel[3] ? 1 : 0);
        int pre = cnt;
#pragma unroll
        for (int off = 1; off < 64; off <<= 1) {
            const int t = __shfl_up(pre, off);
            if (lane >= off) pre += t;
        }
        int p = pre - cnt;
#pragma unroll
        for (int j = 0; j < 4; ++j) {
            if (sel[j]) {
                gl_idx[p] = 4 * tid + j;
                gl_w[p] = w[j];
                ++p;
            }
        }
        if (lane == 63) gl_n = pre;
    }
    __syncthreads();
    const int nsel = gl_n;

    // ---- gather: weighted sum of selected rows in range, 4 row-groups x 128 f4
    const int rs = tid >> 7;
    const int f4 = tid & 127;
    float4 acc = {0.f, 0.f, 0.f, 0.f};
    for (int k = rs; k < nsel; k += 4) {
        const float ww = gl_w[k];
        const float4 t =
            reinterpret_cast<const float4*>(tape + ((size_t)b * NUM_TAPE + gl_idx[k]) * FEATURES)[f4];
        acc.x = fmaf(ww, t.x, acc.x);
        acc.y = fmaf(ww, t.y, acc.y);
        acc.z = fmaf(ww, t.z, acc.z);
        acc.w = fmaf(ww, t.w, acc.w);
    }
    shacc[tid] = acc;
    __syncthreads();
    if (tid < 128) {
        const float4 a0 = shacc[f4];
        const float4 a1 = shacc[128 + f4];
        const float4 a2 = shacc[256 + f4];
        const float4 a3 = shacc[384 + f4];
        float4 r;
        r.x = (a0.x + a1.x) + (a2.x + a3.x);
        r.y = (a0.y + a1.y) + (a2.y + a3.y);
        r.z = (a0.z + a1.z) + (a2.z + a3.z);
        r.w = (a0.w + a1.w) + (a2.w + a3.w);
        reinterpret_cast<float4*>(partials + ((size_t)b * KCHUNKS + kc) * FEATURES)[f4] = r;
    }
}

// ---------------- Kernel C: reduce partials -> token_sel + query update ------------
__global__ __launch_bounds__(512) void k_finish(const float* __restrict__ q,
                                                const float* __restrict__ partials,
                                                float* __restrict__ out) {
    const int b = blockIdx.x;
    const int g = threadIdx.x >> 7;
    const int f4 = threadIdx.x & 127;
    __shared__ float4 sh[512];
    const float4* pp = reinterpret_cast<const float4*>(partials + (size_t)b * KCHUNKS * FEATURES);
    const float4 a = pp[g * 128 + f4];
    const float4 c = pp[(g + 4) * 128 + f4];
    float4 r;
    r.x = a.x + c.x;
    r.y = a.y + c.y;
    r.z = a.z + c.z;
    r.w = a.w + c.w;
    sh[threadIdx.x] = r;
    __syncthreads();
    if (threadIdx.x < 128) {
        const float4 s0 = sh[f4];
        const float4 s1 = sh[128 + f4];
        const float4 s2 = sh[256 + f4];
        const float4 s3 = sh[384 + f4];
        float4 s;
        s.x = (s0.x + s1.x) + (s2.x + s3.x);
        s.y = (s0.y + s1.y) + (s2.y + s3.y);
        s.z = (s0.z + s1.z) + (s2.z + s3.z);
        s.w = (s0.w + s1.w) + (s2.w + s3.w);
        reinterpret_cast<float4*>(out + OFF_TSEL + (size_t)b * FEATURES)[f4] = s;
        if (f4 < 64) {
            const float4 qv = reinterpret_cast<const float4*>(q + (size_t)b * DK)[f4];
            float4 nq;
            nq.x = (qv.x + s.x) * 0.5f;
            nq.y = (qv.y + s.y) * 0.5f;
            nq.z = (qv.z + s.z) * 0.5f;
            nq.w = (qv.w + s.w) * 0.5f;
            reinterpret_cast<float4*>(out + OFF_Q + (size_t)b * DK)[f4] = nq;
        }
    }
}

extern "C" void kernel_launch(void* const* d_in, const int* in_sizes, int n_in,
                              void* d_out, int out_size, void* d_ws, size_t ws_size,
                              hipStream_t stream) {
    const float* q = (const float*)d_in[0];
    const float* hp = (const float*)d_in[1];
    const float* rem = (const float*)d_in[2];
    const float* nup = (const float*)d_in[3];
    const float* mask = (const float*)d_in[4];
    const float* tape = (const float*)d_in[5];
    float* out = (float*)d_out;
    float* ws = (float*)d_ws;

    float* scores = ws + WS_SCORES;
    float* partials = ws + WS_PART;

    k_scores<<<dim3(NUM_TAPE / 32, BATCH), 256, 0, stream>>>(q, tape, scores);
    k_select_gather<<<dim3(KCHUNKS, BATCH), 512, 0, stream>>>(
        scores, mask, hp, rem, nup, tape, partials, out);
    k_finish<<<BATCH, 512, 0, stream>>>(q, partials, out);
}

// Round 9
// 53.534 us; speedup vs baseline: 2.9016x; 1.0068x over previous
//
#include <hip/hip_runtime.h>
#include <math.h>

#define BATCH 64
#define DK 256
#define FEATURES 512
#define NUM_TAPE 2048
#define TOPK 512
#define TOP16 16
#define THRESH 4.0f
#define NSLICE 4
#define CAP 640

// output layout (floats)
#define OFF_Q 0
#define OFF_HP (BATCH * DK)                    /* 16384 */
#define OFF_REM (OFF_HP + BATCH)               /* 16448 */
#define OFF_NUP (OFF_REM + BATCH)              /* 16512 */
#define OFF_MASK (OFF_NUP + BATCH)             /* 16576 */
#define OFF_TSEL (OFF_MASK + BATCH * NUM_TAPE) /* 147648 */

// ws layout (floats)
#define WS_SCORES 0      /* 64*2048 */
#define WS_TOPK 131072   /* int, 64*512 */
#define WS_WEIGHTS 163840

__device__ __forceinline__ unsigned f2key(float f) {
    unsigned u = __float_as_uint(f);
    return (u & 0x80000000u) ? ~u : (u | 0x80000000u);
}

// descending-order bucket find: sh_digit = d with suffix(d) >= KREM > suffix(d+1),
// sh_hi = suffix(d+1). hist[256] valid on entry; threads tid<256 participate.
#define RADIX_FIND(KREM)                                              \
    {                                                                 \
        int v = 0, hcnt = 0;                                          \
        if (tid < 256) {                                              \
            hcnt = hist[tid];                                         \
            v = hcnt;                                                 \
            _Pragma("unroll") for (int off = 1; off < 64; off <<= 1) {\
                const int t = __shfl_down(v, off);                    \
                if (lane + off < 64) v += t;                          \
            }                                                         \
            if (lane == 0) chunkTot[wv] = v;                          \
        }                                                             \
        __syncthreads();                                              \
        if (tid < 256) {                                              \
            _Pragma("unroll") for (int w2 = 0; w2 < 4; ++w2)          \
                if (w2 > wv) v += chunkTot[w2];                       \
            if (v >= (KREM) && (v - hcnt) < (KREM)) {                 \
                sh_digit = tid;                                       \
                sh_hi = v - hcnt;                                     \
            }                                                         \
        }                                                             \
        __syncthreads();                                              \
    }

__device__ __forceinline__ float block_max8(float v, volatile float* redf, int lane, int wv) {
#pragma unroll
    for (int off = 32; off; off >>= 1) v = fmaxf(v, __shfl_xor(v, off));
    if (lane == 0) redf[wv] = v;
    __syncthreads();
#pragma unroll
    for (int w2 = 0; w2 < 8; ++w2) v = fmaxf(v, redf[w2]);
    __syncthreads();
    return v;
}

__device__ __forceinline__ float block_sum8(float v, volatile float* redf, int lane, int wv) {
#pragma unroll
    for (int off = 32; off; off >>= 1) v += __shfl_xor(v, off);
    if (lane == 0) redf[wv] = v;
    __syncthreads();
    float s = 0.f;
#pragma unroll
    for (int w2 = 0; w2 < 8; ++w2) s += redf[w2];
    __syncthreads();
    return s;
}

// ---------------- Kernel A: scores[b][n] = dot(q[b,:256], tape[b,n,:256]) ----------
__global__ __launch_bounds__(256) void k_scores(const float* __restrict__ q,
                                                const float* __restrict__ tape,
                                                float* __restrict__ scores) {
    const int b = blockIdx.y;
    const int wave = threadIdx.x >> 6;
    const int lane = threadIdx.x & 63;
    const float4 qf = reinterpret_cast<const float4*>(q + b * DK)[lane];
    const int base = blockIdx.x * 32;
#pragma unroll
    for (int t = 0; t < 8; ++t) {
        const int tok = base + wave + 4 * t;
        const float4 tf =
            reinterpret_cast<const float4*>(tape + ((size_t)b * NUM_TAPE + tok) * FEATURES)[lane];
        float s = qf.x * tf.x + qf.y * tf.y + qf.z * tf.z + qf.w * tf.w;
#pragma unroll
        for (int off = 32; off; off >>= 1) s += __shfl_xor(s, off);
        if (lane == 0) scores[b * NUM_TAPE + tok] = s;
    }
}

// ------- Kernel B: 3-pass radix select + exact rank + softmax + scalars + mask ------
__global__ __launch_bounds__(512) void k_topk(const float* __restrict__ scores,
                                              const float* __restrict__ mask_in,
                                              const float* __restrict__ hp_in,
                                              const float* __restrict__ rem_in,
                                              const float* __restrict__ nup_in,
                                              int* __restrict__ topk_ws,
                                              float* __restrict__ weights_ws,
                                              float* __restrict__ out) {
    const int b = blockIdx.x;
    const int tid = threadIdx.x;
    const int lane = tid & 63;
    const int wv = tid >> 6;

    __shared__ int hist[256];
    __shared__ int chunkTot[4];
    __shared__ int sh_digit, sh_hi;
    __shared__ unsigned ckey[CAP];
    __shared__ int cidx[CAP];
    __shared__ int csel[CAP];
    __shared__ int cand_n;
    __shared__ float redf[8];
    __shared__ int wtot[8];

    // 4 elements/thread, e = 4*tid + j
    const float4 sc = reinterpret_cast<const float4*>(scores + (size_t)b * NUM_TAPE)[tid];
    const float4 mk = reinterpret_cast<const float4*>(mask_in + (size_t)b * NUM_TAPE)[tid];
    const float4 s0 = reinterpret_cast<const float4*>(scores)[tid]; // row 0 (flatten bug)
    unsigned key[4];
    key[0] = f2key(sc.x - mk.x * 1e9f);
    key[1] = f2key(sc.y - mk.y * 1e9f);
    key[2] = f2key(sc.z - mk.z * 1e9f);
    key[3] = f2key(sc.w - mk.w * 1e9f);
    const float s0v[4] = {s0.x * 0.0625f, s0.y * 0.0625f, s0.z * 0.0625f, s0.w * 0.0625f};

    // ---- select-1 (top-512): pass A on byte3
    if (tid < 256) hist[tid] = 0;
    __syncthreads();
#pragma unroll
    for (int j = 0; j < 4; ++j) atomicAdd(&hist[key[j] >> 24], 1);
    __syncthreads();
    RADIX_FIND(TOPK);
    const unsigned B1 = (unsigned)sh_digit;
    const int above1 = sh_hi;
    __syncthreads();

    // pass B on byte2 among keys with byte3 == B1
    if (tid < 256) hist[tid] = 0;
    __syncthreads();
#pragma unroll
    for (int j = 0; j < 4; ++j)
        if ((key[j] >> 24) == B1) atomicAdd(&hist[(key[j] >> 16) & 0xFF], 1);
    __syncthreads();
    const int kremB = TOPK - above1;
    RADIX_FIND(kremB);
    const unsigned P16 = (B1 << 8) | (unsigned)sh_digit;
    const int krem512 = kremB - sh_hi;
    __syncthreads();

    // candidates (16-bit prefix == P16): exact rank by (key desc, idx asc)
    if (tid == 0) cand_n = 0;
    __syncthreads();
    int cpos[4];
#pragma unroll
    for (int j = 0; j < 4; ++j) {
        cpos[j] = -1;
        if ((key[j] >> 16) == P16) {
            const int p = atomicAdd(&cand_n, 1);
            if (p < CAP) {
                ckey[p] = key[j];
                cidx[p] = 4 * tid + j;
            }
            cpos[j] = p;
        }
    }
    __syncthreads();
    int cn = cand_n < CAP ? cand_n : CAP;
    for (int t = tid; t < cn; t += 512) {
        const unsigned k = ckey[t];
        const int i = cidx[t];
        int r = 0;
        for (int u = 0; u < cn; ++u) {
            const unsigned ko = ckey[u];
            r += (ko > k) || (ko == k && cidx[u] < i);
        }
        csel[t] = (r < krem512);
    }
    __syncthreads();
    bool sel[4];
#pragma unroll
    for (int j = 0; j < 4; ++j)
        sel[j] = ((key[j] >> 16) > P16) ||
                 (cpos[j] >= 0 && cpos[j] < CAP && csel[cpos[j]]);
    __syncthreads();

    // ---- select-2 (top-16 among selected): pass C on byte3 + exact rank
    if (tid < 256) hist[tid] = 0;
    __syncthreads();
#pragma unroll
    for (int j = 0; j < 4; ++j)
        if (sel[j]) atomicAdd(&hist[key[j] >> 24], 1);
    __syncthreads();
    RADIX_FIND(TOP16);
    const unsigned C1 = (unsigned)sh_digit;
    const int krem16 = TOP16 - sh_hi;
    __syncthreads();

    if (tid == 0) cand_n = 0;
    __syncthreads();
    int c2pos[4];
#pragma unroll
    for (int j = 0; j < 4; ++j) {
        c2pos[j] = -1;
        if (sel[j] && (key[j] >> 24) == C1) {
            const int p = atomicAdd(&cand_n, 1);
            if (p < CAP) {
                ckey[p] = key[j];
                cidx[p] = 4 * tid + j;
            }
            c2pos[j] = p;
        }
    }
    __syncthreads();
    cn = cand_n < CAP ? cand_n : CAP;
    for (int t = tid; t < cn; t += 512) {
        const unsigned k = ckey[t];
        const int i = cidx[t];
        int r = 0;
        for (int u = 0; u < cn; ++u) {
            const unsigned ko = ckey[u];
            r += (ko > k) || (ko == k && cidx[u] < i);
        }
        csel[t] = (r < krem16);
    }
    __syncthreads();
    bool in16[4];
#pragma unroll
    for (int j = 0; j < 4; ++j)
        in16[j] = sel[j] && (((key[j] >> 24) > C1) ||
                             (c2pos[j] >= 0 && c2pos[j] < CAP && csel[c2pos[j]]));

    // ---- softmax over row-0 scores at selected elements
    float mloc = -3e38f;
#pragma unroll
    for (int j = 0; j < 4; ++j)
        if (sel[j]) mloc = fmaxf(mloc, s0v[j]);
    const float m = block_max8(mloc, redf, lane, wv);

    float ev[4];
    float eloc = 0.f;
#pragma unroll
    for (int j = 0; j < 4; ++j) {
        ev[j] = sel[j] ? expf(s0v[j] - m) : 0.f;
        eloc += ev[j];
    }
    const float ssum = block_sum8(eloc, redf, lane, wv);
    const float inv = 1.0f / ssum;

    float w[4];
    float lsq = 0.f, l16 = 0.f;
#pragma unroll
    for (int j = 0; j < 4; ++j) {
        w[j] = ev[j] * inv;
        lsq += w[j] * w[j];
        if (in16[j]) l16 += w[j];
    }
    const float sumsq = block_sum8(lsq, redf, lane, wv);
    const float s16 = block_sum8(l16, redf, lane, wv);

    // ---- deterministic compaction (ascending element index) -> topk/weights ws
    {
        const int cnt = (sel[0] ? 1 : 0) + (sel[1] ? 1 : 0) + (sel[2] ? 1 : 0) + (sel[3] ? 1 : 0);
        int pre = cnt;
#pragma unroll
        for (int off = 1; off < 64; off <<= 1) {
            const int t = __shfl_up(pre, off);
            if (lane >= off) pre += t;
        }
        if (lane == 63) wtot[wv] = pre;
        __syncthreads();
        int base = 0;
        for (int w2 = 0; w2 < wv; ++w2) base += wtot[w2];
        int p = base + pre - cnt;
#pragma unroll
        for (int j = 0; j < 4; ++j) {
            if (sel[j]) {
                topk_ws[b * TOPK + p] = 4 * tid + j;
                weights_ws[b * TOPK + p] = w[j];
                ++p;
            }
        }
    }

    // ---- scalars + mask
    if (tid == 0) {
        const float hp = hp_in[b], rem = rem_in[b], nup = nup_in[b];
        const float entropy = 1.0f - sumsq;
        const float still = (hp < THRESH) ? 1.f : 0.f;
        const float nh = ((hp + s16) >= THRESH ? 1.f : 0.f) * still;
        const float st2 = still - nh;
        out[OFF_REM + b] = rem + (nh + st2) * entropy;
        float hp1 = hp + s16 * st2;
        hp1 = hp1 + nh * (THRESH - hp1);
        out[OFF_HP + b] = hp1;
        out[OFF_NUP + b] = nup + st2 + nh;
    }
    float4 om;
    om.x = mk.x + (sel[0] ? 1.f : 0.f);
    om.y = mk.y + (sel[1] ? 1.f : 0.f);
    om.z = mk.z + (sel[2] ? 1.f : 0.f);
    om.w = mk.w + (sel[3] ? 1.f : 0.f);
    reinterpret_cast<float4*>(out + OFF_MASK + (size_t)b * NUM_TAPE)[tid] = om;
}

// ------- Kernel C: feature-sliced gather -> token_sel + query update (no partials) --
// Block (slice, b): computes token_sel[b, slice*128:(slice+1)*128] completely.
// 512 threads = 16 token-groups x 32 f4-lanes.
__global__ __launch_bounds__(512) void k_gather2(const float* __restrict__ tape,
                                                 const int* __restrict__ topk_ws,
                                                 const float* __restrict__ weights_ws,
                                                 const float* __restrict__ q,
                                                 float* __restrict__ out) {
    const int slice = blockIdx.x;  // 0..3
    const int b = blockIdx.y;
    const int tid = threadIdx.x;
    const int tg = tid >> 5;   // 0..15
    const int fl = tid & 31;   // 0..31
    __shared__ float wsh[TOPK];
    __shared__ int ish[TOPK];
    __shared__ float4 shacc[512 + 128];

    wsh[tid] = weights_ws[b * TOPK + tid];
    ish[tid] = topk_ws[b * TOPK + tid];
    __syncthreads();

    const int f4g = slice * 32 + fl;  // global float4 index 0..127
    float4 acc = {0.f, 0.f, 0.f, 0.f};
#pragma unroll 4
    for (int k = tg; k < TOPK; k += 16) {
        const float w = wsh[k];
        const float4 t =
            reinterpret_cast<const float4*>(tape + ((size_t)b * NUM_TAPE + ish[k]) * FEATURES)[f4g];
        acc.x = fmaf(w, t.x, acc.x);
        acc.y = fmaf(w, t.y, acc.y);
        acc.z = fmaf(w, t.z, acc.z);
        acc.w = fmaf(w, t.w, acc.w);
    }
    shacc[tid] = acc;
    __syncthreads();
    // 16 -> 4
    if (tid < 128) {
        const int r = tid >> 5, f2 = tid & 31;
        const float4 a0 = shacc[(4 * r + 0) * 32 + f2];
        const float4 a1 = shacc[(4 * r + 1) * 32 + f2];
        const float4 a2 = shacc[(4 * r + 2) * 32 + f2];
        const float4 a3 = shacc[(4 * r + 3) * 32 + f2];
        float4 s;
        s.x = (a0.x + a1.x) + (a2.x + a3.x);
        s.y = (a0.y + a1.y) + (a2.y + a3.y);
        s.z = (a0.z + a1.z) + (a2.z + a3.z);
        s.w = (a0.w + a1.w) + (a2.w + a3.w);
        shacc[512 + tid] = s;
    }
    __syncthreads();
    // 4 -> 1, write
    if (tid < 32) {
        const float4 p0 = shacc[512 + 0 * 32 + tid];
        const float4 p1 = shacc[512 + 1 * 32 + tid];
        const float4 p2 = shacc[512 + 2 * 32 + tid];
        const float4 p3 = shacc[512 + 3 * 32 + tid];
        float4 s;
        s.x = (p0.x + p1.x) + (p2.x + p3.x);
        s.y = (p0.y + p1.y) + (p2.y + p3.y);
        s.z = (p0.z + p1.z) + (p2.z + p3.z);
        s.w = (p0.w + p1.w) + (p2.w + p3.w);
        reinterpret_cast<float4*>(out + OFF_TSEL + (size_t)b * FEATURES)[slice * 32 + tid] = s;
        if (slice < 2) {
            const float4 qv = reinterpret_cast<const float4*>(q + (size_t)b * DK)[slice * 32 + tid];
            float4 nq;
            nq.x = (qv.x + s.x) * 0.5f;
            nq.y = (qv.y + s.y) * 0.5f;
            nq.z = (qv.z + s.z) * 0.5f;
            nq.w = (qv.w + s.w) * 0.5f;
            reinterpret_cast<float4*>(out + OFF_Q + (size_t)b * DK)[slice * 32 + tid] = nq;
        }
    }
}

extern "C" void kernel_launch(void* const* d_in, const int* in_sizes, int n_in,
                              void* d_out, int out_size, void* d_ws, size_t ws_size,
                              hipStream_t stream) {
    const float* q = (const float*)d_in[0];
    const float* hp = (const float*)d_in[1];
    const float* rem = (const float*)d_in[2];
    const float* nup = (const float*)d_in[3];
    const float* mask = (const float*)d_in[4];
    const float* tape = (const float*)d_in[5];
    float* out = (float*)d_out;
    float* ws = (float*)d_ws;

    float* scores = ws + WS_SCORES;
    int* topk = (int*)(ws + WS_TOPK);
    float* weights = ws + WS_WEIGHTS;

    k_scores<<<dim3(NUM_TAPE / 32, BATCH), 256, 0, stream>>>(q, tape, scores);
    k_topk<<<BATCH, 512, 0, stream>>>(scores, mask, hp, rem, nup, topk, weights, out);
    k_gather2<<<dim3(NSLICE, BATCH), 512, 0, stream>>>(tape, topk, weights, q, out);
}